// Round 1
// baseline (602.229 us; speedup 1.0000x reference)
//
#include <hip/hip_runtime.h>
#include <cstdint>
#include <cstddef>

// Problem constants (from reference): B=2,S=1024 -> T=2048 tokens
#define T_TOK 2048
#define HDIM  1024
#define IDIM  2048
#define NEXP  8

// GEMM tiling
#define BM 128
#define BN 128
#define BK 32
#define BKP 40          // padded LDS B^T row stride (elements): 80 B, non-pow2 -> spreads banks
#define MAXPAD 3072     // max padded routed rows: 2048 + 8*127 rounded to tiles

typedef __attribute__((ext_vector_type(8))) short short8;
typedef __attribute__((ext_vector_type(4))) short short4v;
typedef __attribute__((ext_vector_type(4))) float float4v;

__device__ __forceinline__ short f2bf(float f) {
  // round-to-nearest-even fp32 -> bf16
  uint32_t u = __float_as_uint(f);
  u += 0x7fffu + ((u >> 16) & 1u);
  return (short)(u >> 16);
}

__device__ __forceinline__ void gload_lds16(const void* g, void* l) {
  __builtin_amdgcn_global_load_lds(
      (const __attribute__((address_space(1))) uint32_t*)g,
      (__attribute__((address_space(3))) uint32_t*)l, 16, 0, 0);
}

// ---------------------------------------------------------------- small kernels

__global__ __launch_bounds__(256) void zero_init(int* __restrict__ counts,
                                                 int* __restrict__ perm) {
  int i = threadIdx.x;
  if (i < NEXP) counts[i] = 0;
  for (int p = i; p < MAXPAD; p += 256) perm[p] = 0;
}

// one wave per token: fp32 logits (bitwise-robust argmax vs ref), score, bf16 copies
__global__ __launch_bounds__(256) void router_kernel(
    const float* __restrict__ x, const float* __restrict__ gw,
    short* __restrict__ xbf, short* __restrict__ xsbf,
    int* __restrict__ expert_id, int* __restrict__ slot,
    int* __restrict__ counts) {
  int wv = threadIdx.x >> 6, lane = threadIdx.x & 63;
  int t = blockIdx.x * 4 + wv;
  const float* xr = x + (size_t)t * HDIM;
  float4v xv[4];
  float lg[NEXP];
#pragma unroll
  for (int e = 0; e < NEXP; e++) lg[e] = 0.f;
#pragma unroll
  for (int p = 0; p < 4; p++) {
    xv[p] = *(const float4v*)(xr + p * 256 + lane * 4);
#pragma unroll
    for (int c = 0; c < 4; c++) {
      int h = p * 256 + lane * 4 + c;
      float4v g0 = *(const float4v*)(gw + (size_t)h * NEXP);
      float4v g1 = *(const float4v*)(gw + (size_t)h * NEXP + 4);
      float xc = xv[p][c];
      lg[0] += xc * g0[0]; lg[1] += xc * g0[1];
      lg[2] += xc * g0[2]; lg[3] += xc * g0[3];
      lg[4] += xc * g1[0]; lg[5] += xc * g1[1];
      lg[6] += xc * g1[2]; lg[7] += xc * g1[3];
    }
  }
#pragma unroll
  for (int ofs = 1; ofs < 64; ofs <<= 1) {
#pragma unroll
    for (int e = 0; e < NEXP; e++) lg[e] += __shfl_xor(lg[e], ofs, 64);
  }
  int be = 0;
  float bv = lg[0];
#pragma unroll
  for (int e = 1; e < NEXP; e++) {
    if (lg[e] > bv) { bv = lg[e]; be = e; }
  }
  float score = 1.f / (1.f + __expf(-bv));
  if (lane == 0) {
    expert_id[t] = be;
    slot[t] = atomicAdd(&counts[be], 1);
  }
#pragma unroll
  for (int p = 0; p < 4; p++) {
    short4v b, bs;
#pragma unroll
    for (int c = 0; c < 4; c++) {
      b[c] = f2bf(xv[p][c]);
      bs[c] = f2bf(xv[p][c] * score);
    }
    *(short4v*)(xbf + (size_t)t * HDIM + p * 256 + lane * 4) = b;
    *(short4v*)(xsbf + (size_t)t * HDIM + p * 256 + lane * 4) = bs;
  }
}

// per-expert offsets padded to 128-row tiles (so each row-tile maps to ONE expert)
__global__ void prefix_kernel(const int* __restrict__ counts, int* __restrict__ pad_off) {
  if (threadIdx.x == 0 && blockIdx.x == 0) {
    int run = 0;
    for (int e = 0; e < NEXP; e++) {
      pad_off[e] = run;
      run += (counts[e] + BM - 1) & ~(BM - 1);
    }
    pad_off[NEXP] = run;
  }
}

__global__ __launch_bounds__(256) void build_perm(
    const int* __restrict__ expert_id, const int* __restrict__ slot,
    const int* __restrict__ pad_off, int* __restrict__ perm) {
  int t = blockIdx.x * 256 + threadIdx.x;
  int e = expert_id[t];
  perm[pad_off[e] + slot[t]] = t;
}

// ---------------------------------------------------------------- fused gate/up GEMM + SwiGLU
// act[row][n] = silu(A@Wg) * (A@Wu), A bf16 [rows][1024], W fp32 [1024][2048] (per-expert stride)
template <bool ROUTED>
__global__ __launch_bounds__(256) void gemm1_swiglu(
    const short* __restrict__ A, const float* __restrict__ Wg,
    const float* __restrict__ Wu, short* __restrict__ act,
    const int* __restrict__ pad_off, const int* __restrict__ perm) {
  __shared__ short sA[BM * BK];
  __shared__ short sBg[BN * BKP];
  __shared__ short sBu[BN * BKP];
  int tid = threadIdx.x, lane = tid & 63, wv = tid >> 6;
  int C0 = blockIdx.x * BN, R0 = blockIdx.y * BM;
  const float* wg = Wg;
  const float* wu = Wu;
  if (ROUTED) {
    if (R0 >= pad_off[NEXP]) return;
    int e = 0;
    while (pad_off[e + 1] <= R0) e++;
    size_t wofs = (size_t)e * HDIM * IDIM;
    wg += wofs;
    wu += wofs;
  }
  // A staging: 2 rounds of global_load_lds x16B; LDS dst = tid*16B (wave-uniform + lane*16)
  size_t garow[2];
#pragma unroll
  for (int p = 0; p < 2; p++) {
    int r = R0 + p * 64 + wv * 16 + (lane >> 2);
    int gr = ROUTED ? perm[r] : r;
    garow[p] = (size_t)gr * HDIM + (lane & 3) * 8;
  }
  short* sAdst = sA + (size_t)tid * 8;
  // B staging: thread -> one n column (full lane entropy -> spread banks), 16 k values
  int bn = tid & 127, bkh = (tid >> 7) * 16;
  short* sBgw = sBg + bn * BKP + bkh;
  short* sBuw = sBu + bn * BKP + bkh;

  float4v accg[4][4], accu[4][4];
  float4v z4 = {0.f, 0.f, 0.f, 0.f};
#pragma unroll
  for (int i = 0; i < 4; i++)
#pragma unroll
    for (int j = 0; j < 4; j++) { accg[i][j] = z4; accu[i][j] = z4; }

  const int wrow = (wv >> 1) * 64, wcol = (wv & 1) * 64;
  const int mrow = lane & 15, q8 = (lane >> 4) * 8;

  for (int k0 = 0; k0 < HDIM; k0 += BK) {
    __syncthreads();
    gload_lds16(A + garow[0] + k0, sAdst);
    gload_lds16(A + garow[1] + k0, sAdst + 2048);
    {
      const float* pg = wg + (size_t)(k0 + bkh) * IDIM + C0 + bn;
      const float* pu = wu + (size_t)(k0 + bkh) * IDIM + C0 + bn;
      short8 v0, v1;
#pragma unroll
      for (int j = 0; j < 8; j++) {
        v0[j] = f2bf(pg[(size_t)j * IDIM]);
        v1[j] = f2bf(pg[(size_t)(j + 8) * IDIM]);
      }
      *(short8*)(sBgw) = v0;
      *(short8*)(sBgw + 8) = v1;
#pragma unroll
      for (int j = 0; j < 8; j++) {
        v0[j] = f2bf(pu[(size_t)j * IDIM]);
        v1[j] = f2bf(pu[(size_t)(j + 8) * IDIM]);
      }
      *(short8*)(sBuw) = v0;
      *(short8*)(sBuw + 8) = v1;
    }
    __syncthreads();
    short8 af[4], bg[4], bu[4];
#pragma unroll
    for (int i = 0; i < 4; i++)
      af[i] = *(const short8*)(sA + (wrow + i * 16 + mrow) * BK + q8);
#pragma unroll
    for (int j = 0; j < 4; j++) {
      bg[j] = *(const short8*)(sBg + (wcol + j * 16 + mrow) * BKP + q8);
      bu[j] = *(const short8*)(sBu + (wcol + j * 16 + mrow) * BKP + q8);
    }
#pragma unroll
    for (int i = 0; i < 4; i++)
#pragma unroll
      for (int j = 0; j < 4; j++) {
        accg[i][j] = __builtin_amdgcn_mfma_f32_16x16x32_bf16(af[i], bg[j], accg[i][j], 0, 0, 0);
        accu[i][j] = __builtin_amdgcn_mfma_f32_16x16x32_bf16(af[i], bu[j], accu[i][j], 0, 0, 0);
      }
  }
  // epilogue: silu(g)*u -> bf16
  int qrow = (lane >> 4) * 4, col = lane & 15;
#pragma unroll
  for (int i = 0; i < 4; i++)
#pragma unroll
    for (int j = 0; j < 4; j++)
#pragma unroll
      for (int r = 0; r < 4; r++) {
        int row = R0 + wrow + i * 16 + qrow + r;
        int c = C0 + wcol + j * 16 + col;
        float g = accg[i][j][r], u = accu[i][j][r];
        float sv = g / (1.f + __expf(-g)) * u;
        act[(size_t)row * IDIM + c] = f2bf(sv);
      }
}

// ---------------------------------------------------------------- down GEMM
// shared: out[row][n] = act@Wd ; routed: out[perm[row]][n] += act@Wd (valid rows only)
template <bool ROUTED>
__global__ __launch_bounds__(256) void gemm2_down(
    const short* __restrict__ act, const float* __restrict__ Wd,
    float* __restrict__ out, const int* __restrict__ pad_off,
    const int* __restrict__ counts, const int* __restrict__ perm) {
  __shared__ short sA[BM * BK];
  __shared__ short sB[BN * BKP];
  int tid = threadIdx.x, lane = tid & 63, wv = tid >> 6;
  int C0 = blockIdx.x * BN, R0 = blockIdx.y * BM;
  const float* wd = Wd;
  int e = 0;
  if (ROUTED) {
    if (R0 >= pad_off[NEXP]) return;
    while (pad_off[e + 1] <= R0) e++;
    wd += (size_t)e * IDIM * HDIM;
  }
  size_t garow[2];
#pragma unroll
  for (int p = 0; p < 2; p++) {
    int r = R0 + p * 64 + wv * 16 + (lane >> 2);
    garow[p] = (size_t)r * IDIM + (lane & 3) * 8;  // act rows are direct (padded space)
  }
  short* sAdst = sA + (size_t)tid * 8;
  int bn = tid & 127, bkh = (tid >> 7) * 16;
  short* sBw = sB + bn * BKP + bkh;

  float4v acc[4][4];
  float4v z4 = {0.f, 0.f, 0.f, 0.f};
#pragma unroll
  for (int i = 0; i < 4; i++)
#pragma unroll
    for (int j = 0; j < 4; j++) acc[i][j] = z4;

  const int wrow = (wv >> 1) * 64, wcol = (wv & 1) * 64;
  const int mrow = lane & 15, q8 = (lane >> 4) * 8;

  for (int k0 = 0; k0 < IDIM; k0 += BK) {
    __syncthreads();
    gload_lds16(act + garow[0] + k0, sAdst);
    gload_lds16(act + garow[1] + k0, sAdst + 2048);
    {
      const float* pd = wd + (size_t)(k0 + bkh) * HDIM + C0 + bn;
      short8 v0, v1;
#pragma unroll
      for (int j = 0; j < 8; j++) {
        v0[j] = f2bf(pd[(size_t)j * HDIM]);
        v1[j] = f2bf(pd[(size_t)(j + 8) * HDIM]);
      }
      *(short8*)(sBw) = v0;
      *(short8*)(sBw + 8) = v1;
    }
    __syncthreads();
    short8 af[4], bf[4];
#pragma unroll
    for (int i = 0; i < 4; i++)
      af[i] = *(const short8*)(sA + (wrow + i * 16 + mrow) * BK + q8);
#pragma unroll
    for (int j = 0; j < 4; j++)
      bf[j] = *(const short8*)(sB + (wcol + j * 16 + mrow) * BKP + q8);
#pragma unroll
    for (int i = 0; i < 4; i++)
#pragma unroll
      for (int j = 0; j < 4; j++)
        acc[i][j] = __builtin_amdgcn_mfma_f32_16x16x32_bf16(af[i], bf[j], acc[i][j], 0, 0, 0);
  }
  int qrow = (lane >> 4) * 4, col = lane & 15;
#pragma unroll
  for (int i = 0; i < 4; i++)
#pragma unroll
    for (int j = 0; j < 4; j++)
#pragma unroll
      for (int r = 0; r < 4; r++) {
        int rowp = R0 + wrow + i * 16 + qrow + r;
        int c = C0 + wcol + j * 16 + col;
        float v = acc[i][j][r];
        if (ROUTED) {
          if (rowp - pad_off[e] < counts[e]) {
            int tok = perm[rowp];
            out[(size_t)tok * HDIM + c] += v;
          }
        } else {
          out[(size_t)rowp * HDIM + c] = v;
        }
      }
}

// ---------------------------------------------------------------- launch

extern "C" void kernel_launch(void* const* d_in, const int* in_sizes, int n_in,
                              void* d_out, int out_size, void* d_ws, size_t ws_size,
                              hipStream_t stream) {
  const float* x       = (const float*)d_in[0];  // [T,H]
  const float* gate_w  = (const float*)d_in[1];  // [H,E]
  const float* sh_gate = (const float*)d_in[2];  // [H,I]
  const float* sh_up   = (const float*)d_in[3];
  const float* sh_down = (const float*)d_in[4];  // [I,H]
  const float* rt_gate = (const float*)d_in[5];  // [E,H,I]
  const float* rt_up   = (const float*)d_in[6];
  const float* rt_down = (const float*)d_in[7];  // [E,I,H]
  float* out = (float*)d_out;

  char* w = (char*)d_ws;
  short* xbf    = (short*)(w);                         // 4 MB
  short* xsbf   = (short*)(w + (size_t)4 * 1024 * 1024);
  short* act_sh = (short*)(w + (size_t)8 * 1024 * 1024);   // 8 MB
  short* act_rt = (short*)(w + (size_t)16 * 1024 * 1024);  // 12 MB
  int* ints     = (int*)(w + (size_t)29 * 1024 * 1024);
  int* counts    = ints;            // 8
  int* pad_off   = ints + 8;        // 9
  int* expert_id = ints + 32;       // 2048
  int* slot      = ints + 32 + 2048;
  int* perm      = ints + 32 + 4096;  // 3072

  zero_init<<<1, 256, 0, stream>>>(counts, perm);
  router_kernel<<<T_TOK / 4, 256, 0, stream>>>(x, gate_w, xbf, xsbf, expert_id, slot, counts);
  prefix_kernel<<<1, 64, 0, stream>>>(counts, pad_off);
  build_perm<<<T_TOK / 256, 256, 0, stream>>>(expert_id, slot, pad_off, perm);

  gemm1_swiglu<false><<<dim3(IDIM / BN, T_TOK / BM), 256, 0, stream>>>(
      xbf, sh_gate, sh_up, act_sh, nullptr, nullptr);
  gemm1_swiglu<true><<<dim3(IDIM / BN, MAXPAD / BM), 256, 0, stream>>>(
      xsbf, rt_gate, rt_up, act_rt, pad_off, perm);

  gemm2_down<false><<<dim3(HDIM / BN, T_TOK / BM), 256, 0, stream>>>(
      act_sh, sh_down, out, nullptr, nullptr, nullptr);
  gemm2_down<true><<<dim3(HDIM / BN, MAXPAD / BM), 256, 0, stream>>>(
      act_rt, rt_down, out, pad_off, counts, perm);
}

// Round 2
// 438.524 us; speedup vs baseline: 1.3733x; 1.3733x over previous
//
#include <hip/hip_runtime.h>
#include <cstdint>
#include <cstddef>

// B=2,S=1024 -> T=2048 tokens
#define T_TOK 2048
#define HDIM  1024
#define IDIM  2048
#define NEXP  8

#define BM 128
#define BK 32
#define BN2 64          // gemm2 col tile
#define MAXPAD 3072
#define SH_TILES 16     // T_TOK/BM
#define RT_TILES 24     // MAXPAD/BM

typedef __attribute__((ext_vector_type(8))) short short8;
typedef __attribute__((ext_vector_type(4))) short short4v;
typedef __attribute__((ext_vector_type(4))) float float4v;

__device__ __forceinline__ short f2bf(float f) {
  uint32_t u = __float_as_uint(f);
  u += 0x7fffu + ((u >> 16) & 1u);
  return (short)(u >> 16);
}

__device__ __forceinline__ void gload_lds16(const void* g, void* l) {
  __builtin_amdgcn_global_load_lds(
      (const __attribute__((address_space(1))) uint32_t*)g,
      (__attribute__((address_space(3))) uint32_t*)l, 16, 0, 0);
}

// 16B-chunk XOR swizzle: bits[1:0] ^= bits[5:4]. Self-inverse (bits 5:4 preserved).
// Staging lane->global mapping is free, so this costs nothing; makes fragment
// ds_read_b128 2-way bank aliased (free per m136) instead of 8-way.
__device__ __forceinline__ int swz(int c) { return c ^ ((c >> 4) & 3); }

// ---------------------------------------------------------------- small kernels

__global__ __launch_bounds__(256) void zero_init(int* __restrict__ counts,
                                                 int* __restrict__ perm) {
  int i = threadIdx.x;
  if (i < NEXP) counts[i] = 0;
  for (int p = i; p < MAXPAD; p += 256) perm[p] = 0;
}

// one wave per token: fp32 logits (exact argmax vs ref), score, bf16 copies
__global__ __launch_bounds__(256) void router_kernel(
    const float* __restrict__ x, const float* __restrict__ gw,
    short* __restrict__ xbf, short* __restrict__ xsbf,
    int* __restrict__ expert_id, int* __restrict__ slot,
    int* __restrict__ counts) {
  int wv = threadIdx.x >> 6, lane = threadIdx.x & 63;
  int t = blockIdx.x * 4 + wv;
  const float* xr = x + (size_t)t * HDIM;
  float4v xv[4];
  float lg[NEXP];
#pragma unroll
  for (int e = 0; e < NEXP; e++) lg[e] = 0.f;
#pragma unroll
  for (int p = 0; p < 4; p++) {
    xv[p] = *(const float4v*)(xr + p * 256 + lane * 4);
#pragma unroll
    for (int c = 0; c < 4; c++) {
      int h = p * 256 + lane * 4 + c;
      float4v g0 = *(const float4v*)(gw + (size_t)h * NEXP);
      float4v g1 = *(const float4v*)(gw + (size_t)h * NEXP + 4);
      float xc = xv[p][c];
      lg[0] += xc * g0[0]; lg[1] += xc * g0[1];
      lg[2] += xc * g0[2]; lg[3] += xc * g0[3];
      lg[4] += xc * g1[0]; lg[5] += xc * g1[1];
      lg[6] += xc * g1[2]; lg[7] += xc * g1[3];
    }
  }
#pragma unroll
  for (int ofs = 1; ofs < 64; ofs <<= 1) {
#pragma unroll
    for (int e = 0; e < NEXP; e++) lg[e] += __shfl_xor(lg[e], ofs, 64);
  }
  int be = 0;
  float bv = lg[0];
#pragma unroll
  for (int e = 1; e < NEXP; e++) {
    if (lg[e] > bv) { bv = lg[e]; be = e; }
  }
  float score = 1.f / (1.f + __expf(-bv));
  if (lane == 0) {
    expert_id[t] = be;
    slot[t] = atomicAdd(&counts[be], 1);
  }
#pragma unroll
  for (int p = 0; p < 4; p++) {
    short4v b, bs;
#pragma unroll
    for (int c = 0; c < 4; c++) {
      b[c] = f2bf(xv[p][c]);
      bs[c] = f2bf(xv[p][c] * score);
    }
    *(short4v*)(xbf + (size_t)t * HDIM + p * 256 + lane * 4) = b;
    *(short4v*)(xsbf + (size_t)t * HDIM + p * 256 + lane * 4) = bs;
  }
}

__global__ void prefix_kernel(const int* __restrict__ counts, int* __restrict__ pad_off) {
  if (threadIdx.x == 0 && blockIdx.x == 0) {
    int run = 0;
    for (int e = 0; e < NEXP; e++) {
      pad_off[e] = run;
      run += (counts[e] + BM - 1) & ~(BM - 1);
    }
    pad_off[NEXP] = run;
  }
}

__global__ __launch_bounds__(256) void build_perm(
    const int* __restrict__ expert_id, const int* __restrict__ slot,
    const int* __restrict__ pad_off, int* __restrict__ perm) {
  int t = blockIdx.x * 256 + threadIdx.x;
  int e = expert_id[t];
  perm[pad_off[e] + slot[t]] = t;
}

// ---------------------------------------------------------------- weight transpose+convert
// src fp32 [R][C] -> dst bf16 [C][R]; one pass = one 64x64 tile, LDS-staged.

__global__ __launch_bounds__(256) void transpose_w1(
    const float* __restrict__ shg, const float* __restrict__ shu,
    const float* __restrict__ rtg, const float* __restrict__ rtu,
    short* __restrict__ shg_t, short* __restrict__ shu_t,
    short* __restrict__ rtg_t, short* __restrict__ rtu_t) {
  __shared__ __align__(16) short t[64][66];
  int z = blockIdx.z;
  const float *s0, *s1;
  short *d0, *d1;
  if (z == 0) { s0 = shg; s1 = shu; d0 = shg_t; d1 = shu_t; }
  else {
    size_t o = (size_t)(z - 1) * HDIM * IDIM;
    s0 = rtg + o; s1 = rtu + o; d0 = rtg_t + o; d1 = rtu_t + o;
  }
  const int R = HDIM, C = IDIM;
  int r0 = blockIdx.y * 64, c0 = blockIdx.x * 64;
  int tid = threadIdx.x;
  int tr = tid >> 4, tc = (tid & 15) * 4;
  int oc = tid >> 2, rs = (tid & 3) * 16;
#pragma unroll
  for (int pass = 0; pass < 2; pass++) {
    const float* s = pass ? s1 : s0;
    short* d = pass ? d1 : d0;
    if (pass) __syncthreads();
#pragma unroll
    for (int i = 0; i < 4; i++) {
      float4v v = *(const float4v*)(s + (size_t)(r0 + tr + i * 16) * C + c0 + tc);
      int w0 = (int)(unsigned short)f2bf(v[0]) | ((int)f2bf(v[1]) << 16);
      int w1 = (int)(unsigned short)f2bf(v[2]) | ((int)f2bf(v[3]) << 16);
      int* p = (int*)&t[tr + i * 16][tc];
      p[0] = w0;
      p[1] = w1;
    }
    __syncthreads();
    short8 o0, o1;
#pragma unroll
    for (int j = 0; j < 8; j++) { o0[j] = t[rs + j][oc]; o1[j] = t[rs + 8 + j][oc]; }
    short* dp = d + (size_t)(c0 + oc) * R + r0 + rs;
    *(short8*)dp = o0;
    *(short8*)(dp + 8) = o1;
  }
}

__global__ __launch_bounds__(256) void transpose_w2(
    const float* __restrict__ shd, const float* __restrict__ rtd,
    short* __restrict__ shd_t, short* __restrict__ rtd_t) {
  __shared__ __align__(16) short t[64][66];
  int z = blockIdx.z;
  const float* s = (z == 0) ? shd : rtd + (size_t)(z - 1) * IDIM * HDIM;
  short* d = (z == 0) ? shd_t : rtd_t + (size_t)(z - 1) * IDIM * HDIM;
  const int R = IDIM, C = HDIM;
  int r0 = blockIdx.y * 64, c0 = blockIdx.x * 64;
  int tid = threadIdx.x;
  int tr = tid >> 4, tc = (tid & 15) * 4;
  int oc = tid >> 2, rs = (tid & 3) * 16;
#pragma unroll
  for (int i = 0; i < 4; i++) {
    float4v v = *(const float4v*)(s + (size_t)(r0 + tr + i * 16) * C + c0 + tc);
    int w0 = (int)(unsigned short)f2bf(v[0]) | ((int)f2bf(v[1]) << 16);
    int w1 = (int)(unsigned short)f2bf(v[2]) | ((int)f2bf(v[3]) << 16);
    int* p = (int*)&t[tr + i * 16][tc];
    p[0] = w0;
    p[1] = w1;
  }
  __syncthreads();
  short8 o0, o1;
#pragma unroll
  for (int j = 0; j < 8; j++) { o0[j] = t[rs + j][oc]; o1[j] = t[rs + 8 + j][oc]; }
  short* dp = d + (size_t)(c0 + oc) * R + r0 + rs;
  *(short8*)dp = o0;
  *(short8*)(dp + 8) = o1;
}

// ---------------------------------------------------------------- gemm1: act = silu(A Wg) * (A Wu)
// A bf16 [rows][1024]; B^T bf16 [2048 n][1024 k]. m97 structure: all staging
// via global_load_lds x16B; LDS [row][32k] 64B rows, XOR-swizzled chunks.
// grid y: [0,16) shared tiles, [16,40) routed padded tiles.

__global__ __launch_bounds__(256) void gemm1_swiglu(
    const short* __restrict__ xbf, const short* __restrict__ xsbf,
    const short* __restrict__ shg_t, const short* __restrict__ shu_t,
    const short* __restrict__ rtg_t, const short* __restrict__ rtu_t,
    short* __restrict__ act_sh, short* __restrict__ act_rt,
    const int* __restrict__ pad_off, const int* __restrict__ perm) {
  __shared__ __align__(1024) short sA[BM * BK];
  __shared__ __align__(1024) short sBg[BM * BK];
  __shared__ __align__(1024) short sBu[BM * BK];
  int tid = threadIdx.x, lane = tid & 63, wv = tid >> 6;
  int C0 = blockIdx.x * 128;
  int y = blockIdx.y;
  const short *A, *Bg, *Bu;
  short* act;
  int R0;
  bool routed = (y >= SH_TILES);
  if (!routed) {
    A = xbf; Bg = shg_t; Bu = shu_t; act = act_sh; R0 = y * BM;
  } else {
    R0 = (y - SH_TILES) * BM;
    if (R0 >= pad_off[NEXP]) return;
    int e = 0;
    while (pad_off[e + 1] <= R0) e++;
    size_t o = (size_t)e * HDIM * IDIM;
    A = xsbf; Bg = rtg_t + o; Bu = rtu_t + o; act = act_rt;
  }
  // staging addresses: phys chunk p = tid (+256), global chunk c = swz(p)
  int c0 = swz(tid), c1 = swz(tid + 256);
  int r0c = c0 >> 2, r1c = c1 >> 2;
  int ar0 = routed ? perm[R0 + r0c] : R0 + r0c;
  int ar1 = routed ? perm[R0 + r1c] : R0 + r1c;
  size_t gA0 = (size_t)ar0 * HDIM + (c0 & 3) * 8;
  size_t gA1 = (size_t)ar1 * HDIM + (c1 & 3) * 8;
  size_t gB0 = (size_t)(C0 + r0c) * HDIM + (c0 & 3) * 8;
  size_t gB1 = (size_t)(C0 + r1c) * HDIM + (c1 & 3) * 8;
  short* lds0 = (short*)nullptr;
  (void)lds0;
  short* lA0 = sA + tid * 8;  short* lA1 = sA + (tid + 256) * 8;
  short* lG0 = sBg + tid * 8; short* lG1 = sBg + (tid + 256) * 8;
  short* lU0 = sBu + tid * 8; short* lU1 = sBu + (tid + 256) * 8;

  float4v accg[4][4], accu[4][4];
  float4v z4 = {0.f, 0.f, 0.f, 0.f};
#pragma unroll
  for (int i = 0; i < 4; i++)
#pragma unroll
    for (int j = 0; j < 4; j++) { accg[i][j] = z4; accu[i][j] = z4; }

  const int wrow = (wv >> 1) * 64, wcol = (wv & 1) * 64;
  const int mrow = lane & 15, h4 = lane >> 4;
  int aoff[4], boff[4];
#pragma unroll
  for (int i = 0; i < 4; i++)
    aoff[i] = swz(((wrow + i * 16 + mrow) << 2) + h4) * 8;
#pragma unroll
  for (int j = 0; j < 4; j++)
    boff[j] = swz(((wcol + j * 16 + mrow) << 2) + h4) * 8;

  for (int k0 = 0; k0 < HDIM; k0 += BK) {
    __syncthreads();
    gload_lds16(A + gA0 + k0, lA0);
    gload_lds16(A + gA1 + k0, lA1);
    gload_lds16(Bg + gB0 + k0, lG0);
    gload_lds16(Bg + gB1 + k0, lG1);
    gload_lds16(Bu + gB0 + k0, lU0);
    gload_lds16(Bu + gB1 + k0, lU1);
    __syncthreads();
    short8 af[4], bg[4], bu[4];
#pragma unroll
    for (int i = 0; i < 4; i++) af[i] = *(const short8*)(sA + aoff[i]);
#pragma unroll
    for (int j = 0; j < 4; j++) {
      bg[j] = *(const short8*)(sBg + boff[j]);
      bu[j] = *(const short8*)(sBu + boff[j]);
    }
#pragma unroll
    for (int i = 0; i < 4; i++)
#pragma unroll
      for (int j = 0; j < 4; j++) {
        accg[i][j] = __builtin_amdgcn_mfma_f32_16x16x32_bf16(af[i], bg[j], accg[i][j], 0, 0, 0);
        accu[i][j] = __builtin_amdgcn_mfma_f32_16x16x32_bf16(af[i], bu[j], accu[i][j], 0, 0, 0);
      }
  }
  int qrow = h4 * 4, col = mrow;
#pragma unroll
  for (int i = 0; i < 4; i++)
#pragma unroll
    for (int j = 0; j < 4; j++)
#pragma unroll
      for (int r = 0; r < 4; r++) {
        int row = R0 + wrow + i * 16 + qrow + r;
        int c = C0 + wcol + j * 16 + col;
        float g = accg[i][j][r], u = accu[i][j][r];
        float sv = g / (1.f + __expf(-g)) * u;
        act[(size_t)row * IDIM + c] = f2bf(sv);
      }
}

// ---------------------------------------------------------------- gemm2: out = act Wd^T-form
// A bf16 [rows][2048]; B^T bf16 [1024 n][2048 k]. BN=64 for grid size.
// shared tiles -> plain store to d_out; routed -> store to rt_out (scatter, one
// writer per token), separate add kernel combines (avoids intra-dispatch race).

__global__ __launch_bounds__(256) void gemm2_down(
    const short* __restrict__ act_sh, const short* __restrict__ act_rt,
    const short* __restrict__ shd_t, const short* __restrict__ rtd_t,
    float* __restrict__ out, float* __restrict__ rt_out,
    const int* __restrict__ pad_off, const int* __restrict__ counts,
    const int* __restrict__ perm) {
  __shared__ __align__(1024) short sA[BM * BK];
  __shared__ __align__(1024) short sB[BN2 * BK];
  int tid = threadIdx.x, lane = tid & 63, wv = tid >> 6;
  int C0 = blockIdx.x * BN2;
  int y = blockIdx.y;
  const short *A, *Bd;
  int R0, e = 0;
  bool routed = (y >= SH_TILES);
  if (!routed) {
    A = act_sh; Bd = shd_t; R0 = y * BM;
  } else {
    R0 = (y - SH_TILES) * BM;
    if (R0 >= pad_off[NEXP]) return;
    while (pad_off[e + 1] <= R0) e++;
    A = act_rt; Bd = rtd_t + (size_t)e * IDIM * HDIM;
  }
  int c0 = swz(tid), c1 = swz(tid + 256);
  size_t gA0 = (size_t)(R0 + (c0 >> 2)) * IDIM + (c0 & 3) * 8;
  size_t gA1 = (size_t)(R0 + (c1 >> 2)) * IDIM + (c1 & 3) * 8;
  size_t gB0 = (size_t)(C0 + (c0 >> 2)) * IDIM + (c0 & 3) * 8;  // c0>>2 in 0..63 over first 256 chunks? no: tid<256 -> c0<256 -> rows 0..63 OK for B
  short* lA0 = sA + tid * 8;
  short* lA1 = sA + (tid + 256) * 8;
  short* lB0 = sB + tid * 8;

  float4v acc[2][4];
  float4v z4 = {0.f, 0.f, 0.f, 0.f};
#pragma unroll
  for (int i = 0; i < 2; i++)
#pragma unroll
    for (int j = 0; j < 4; j++) acc[i][j] = z4;

  const int wrow = wv * 32;
  const int mrow = lane & 15, h4 = lane >> 4;
  int aoff[2], boff[4];
#pragma unroll
  for (int i = 0; i < 2; i++)
    aoff[i] = swz(((wrow + i * 16 + mrow) << 2) + h4) * 8;
#pragma unroll
  for (int j = 0; j < 4; j++)
    boff[j] = swz(((j * 16 + mrow) << 2) + h4) * 8;

  for (int k0 = 0; k0 < IDIM; k0 += BK) {
    __syncthreads();
    gload_lds16(A + gA0 + k0, lA0);
    gload_lds16(A + gA1 + k0, lA1);
    gload_lds16(Bd + gB0 + k0, lB0);
    __syncthreads();
    short8 af[2], bf4[4];
#pragma unroll
    for (int i = 0; i < 2; i++) af[i] = *(const short8*)(sA + aoff[i]);
#pragma unroll
    for (int j = 0; j < 4; j++) bf4[j] = *(const short8*)(sB + boff[j]);
#pragma unroll
    for (int i = 0; i < 2; i++)
#pragma unroll
      for (int j = 0; j < 4; j++)
        acc[i][j] = __builtin_amdgcn_mfma_f32_16x16x32_bf16(af[i], bf4[j], acc[i][j], 0, 0, 0);
  }
  int qrow = h4 * 4, col = mrow;
#pragma unroll
  for (int i = 0; i < 2; i++)
#pragma unroll
    for (int j = 0; j < 4; j++)
#pragma unroll
      for (int r = 0; r < 4; r++) {
        int row = R0 + wrow + i * 16 + qrow + r;
        int c = C0 + j * 16 + col;
        float v = acc[i][j][r];
        if (!routed) {
          out[(size_t)row * HDIM + c] = v;
        } else if (row - pad_off[e] < counts[e]) {
          rt_out[(size_t)perm[row] * HDIM + c] = v;
        }
      }
}

__global__ __launch_bounds__(256) void add_routed(float* __restrict__ out,
                                                  const float* __restrict__ rt_out) {
  size_t i = ((size_t)blockIdx.x * 256 + threadIdx.x) * 4;
  float4v a = *(const float4v*)(out + i);
  float4v b = *(const float4v*)(rt_out + i);
  a[0] += b[0]; a[1] += b[1]; a[2] += b[2]; a[3] += b[3];
  *(float4v*)(out + i) = a;
}

// ---------------------------------------------------------------- launch

extern "C" void kernel_launch(void* const* d_in, const int* in_sizes, int n_in,
                              void* d_out, int out_size, void* d_ws, size_t ws_size,
                              hipStream_t stream) {
  const float* x       = (const float*)d_in[0];
  const float* gate_w  = (const float*)d_in[1];
  const float* sh_gate = (const float*)d_in[2];
  const float* sh_up   = (const float*)d_in[3];
  const float* sh_down = (const float*)d_in[4];
  const float* rt_gate = (const float*)d_in[5];
  const float* rt_up   = (const float*)d_in[6];
  const float* rt_down = (const float*)d_in[7];
  float* out = (float*)d_out;

  char* w = (char*)d_ws;
  const size_t MB = 1024 * 1024;
  short* xbf    = (short*)(w + 0 * MB);    // 4 MB  [2048][1024] bf16
  short* xsbf   = (short*)(w + 4 * MB);    // 4 MB
  short* act_sh = (short*)(w + 8 * MB);    // 8 MB  [2048][2048]
  short* act_rt = (short*)(w + 16 * MB);   // 12 MB [3072][2048]
  float* rt_out = (float*)(w + 28 * MB);   // 8 MB  [2048][1024] fp32
  short* shg_t  = (short*)(w + 36 * MB);   // 4 MB  [2048][1024]
  short* shu_t  = (short*)(w + 40 * MB);   // 4 MB
  short* shd_t  = (short*)(w + 44 * MB);   // 4 MB  [1024][2048]
  short* rtg_t  = (short*)(w + 48 * MB);   // 32 MB [8][2048][1024]
  short* rtu_t  = (short*)(w + 80 * MB);   // 32 MB
  short* rtd_t  = (short*)(w + 112 * MB);  // 32 MB [8][1024][2048]
  int* ints     = (int*)(w + 144 * MB);
  int* counts    = ints;
  int* pad_off   = ints + 8;
  int* expert_id = ints + 32;
  int* slot      = ints + 32 + 2048;
  int* perm      = ints + 32 + 4096;

  zero_init<<<1, 256, 0, stream>>>(counts, perm);
  router_kernel<<<T_TOK / 4, 256, 0, stream>>>(x, gate_w, xbf, xsbf, expert_id, slot, counts);
  prefix_kernel<<<1, 64, 0, stream>>>(counts, pad_off);
  build_perm<<<T_TOK / 256, 256, 0, stream>>>(expert_id, slot, pad_off, perm);

  transpose_w1<<<dim3(IDIM / 64, HDIM / 64, 1 + NEXP), 256, 0, stream>>>(
      sh_gate, sh_up, rt_gate, rt_up, shg_t, shu_t, rtg_t, rtu_t);
  transpose_w2<<<dim3(HDIM / 64, IDIM / 64, 1 + NEXP), 256, 0, stream>>>(
      sh_down, rt_down, shd_t, rtd_t);

  gemm1_swiglu<<<dim3(IDIM / 128, SH_TILES + RT_TILES), 256, 0, stream>>>(
      xbf, xsbf, shg_t, shu_t, rtg_t, rtu_t, act_sh, act_rt, pad_off, perm);

  gemm2_down<<<dim3(HDIM / BN2, SH_TILES + RT_TILES), 256, 0, stream>>>(
      act_sh, act_rt, shd_t, rtd_t, out, rt_out, pad_off, counts, perm);

  add_routed<<<(T_TOK * HDIM) / (256 * 4), 256, 0, stream>>>(out, rt_out);
}